// Round 15
// baseline (139.040 us; speedup 1.0000x reference)
//
#include <hip/hip_runtime.h>
#include <math.h>

#define BB 8
#define CC 256
#define CI 128
#define NN 4096
#define BN_EPS 1e-5f
#define LOG2E 1.4426950408889634f
#define FIXMAX 88.0f

typedef unsigned int uint;
typedef unsigned short ushort;
typedef __bf16 bf16x8 __attribute__((ext_vector_type(8)));
typedef _Float16 f16x8 __attribute__((ext_vector_type(8)));
typedef float f32x16 __attribute__((ext_vector_type(16)));

__device__ __forceinline__ ushort bfbits(float f) {
    return __builtin_bit_cast(ushort, (__bf16)f);
}
__device__ __forceinline__ ushort hbits(float f) {
    return __builtin_bit_cast(ushort, (_Float16)f);
}
__device__ __forceinline__ float bf2f(ushort h) {
    return __uint_as_float(((uint)h) << 16);
}
__device__ __forceinline__ float bflo(uint v) { return __uint_as_float(v << 16); }
__device__ __forceinline__ float bfhi(uint v) { return __uint_as_float(v & 0xffff0000u); }
__device__ __forceinline__ uint pk2(float a, float b) {
    return (uint)bfbits(a) | ((uint)bfbits(b) << 16);
}
__device__ __forceinline__ void gload16(const void* g, void* l) {
    __builtin_amdgcn_global_load_lds(
        (const __attribute__((address_space(1))) uint*)g,
        (__attribute__((address_space(3))) uint*)l, 16, 0, 0);
}
__device__ __forceinline__ bf16x8 asbf8(uint4 v) { return __builtin_bit_cast(bf16x8, v); }
__device__ __forceinline__ float fexp2(float a) {
    float e;
    asm("v_exp_f32 %0, %1" : "=v"(e) : "v"(a));
    return e;
}

// ---------------------------------------------------------------------------
// Kernel 0: weight conversion to split-bf16, fragment-major [cs][h][o].
// ---------------------------------------------------------------------------
__global__ __launch_bounds__(256) void wconv_kernel(
    const float* __restrict__ w_t, const float* __restrict__ w_p,
    const float* __restrict__ w_g, const float* __restrict__ w_o,
    const float* __restrict__ bn_g, const float* __restrict__ bn_b,
    const float* __restrict__ bn_m, const float* __restrict__ bn_v,
    const float* __restrict__ b_out,
    uint4* __restrict__ wt_h, uint4* __restrict__ wt_l,
    uint4* __restrict__ wp_h, uint4* __restrict__ wp_l,
    uint4* __restrict__ wg_h, uint4* __restrict__ wg_l,
    uint4* __restrict__ wo_h, uint4* __restrict__ wo_l,
    float* __restrict__ scale, float* __restrict__ shift)
{
    const int t = threadIdx.x, blk = blockIdx.x;
    if (blk == 64) {
        float inv = bn_g[t] * rsqrtf(bn_v[t] + BN_EPS);
        scale[t] = inv;
        shift[t] = b_out[t] * inv + bn_b[t] - bn_m[t] * inv;
        return;
    }
    int u = blk * 256 + t;
    int mat = u >> 12, ul = u & 4095;
    const float* src;
    uint4 *dh, *dl;
    int o, oct, C, O;
    if (mat == 0)      { src = w_t; dh = wt_h; dl = wt_l; }
    else if (mat == 1) { src = w_p; dh = wp_h; dl = wp_l; }
    else if (mat == 2) { src = w_g; dh = wg_h; dl = wg_l; }
    else               { src = w_o; dh = wo_h; dl = wo_l; }
    if (mat < 3) { O = 128; C = 256; o = ul >> 5; oct = ul & 31; }
    else         { O = 256; C = 128; o = ul >> 4; oct = ul & 15; }
    const float* s = src + (size_t)o * C + oct * 8;
    float4 va = *(const float4*)s, vb = *(const float4*)(s + 4);
    float v[8] = {va.x, va.y, va.z, va.w, vb.x, vb.y, vb.z, vb.w};
    uint hw[4], lw[4];
#pragma unroll
    for (int j = 0; j < 4; j++) {
        float a = v[2 * j], c = v[2 * j + 1];
        ushort ha = bfbits(a), hc = bfbits(c);
        hw[j] = (uint)ha | ((uint)hc << 16);
        lw[j] = pk2(a - bf2f(ha), c - bf2f(hc));
    }
    int di = oct * O + o;
    dh[di] = make_uint4(hw[0], hw[1], hw[2], hw[3]);
    dl[di] = make_uint4(lw[0], lw[1], lw[2], lw[3]);
}

// ---------------------------------------------------------------------------
// Kernel 1: fused theta/phi/g projections via MFMA (3-term split-bf16 ==
// ~f32 accuracy internally). theta/phi stored FP16 (exp2-domain theta) for
// the fp16 QK MFMA; g stored transposed bf16 for the PV MFMA.
// ---------------------------------------------------------------------------
__global__ __launch_bounds__(256, 2) void proj3_mfma(
    const float* __restrict__ x,
    const uint4* __restrict__ wt_h, const uint4* __restrict__ wt_l,
    const uint4* __restrict__ wp_h, const uint4* __restrict__ wp_l,
    const uint4* __restrict__ wg_h, const uint4* __restrict__ wg_l,
    const float* __restrict__ b_t, const float* __restrict__ b_p,
    const float* __restrict__ b_g,
    ushort* __restrict__ th, ushort* __restrict__ phi, ushort* __restrict__ gT)
{
    __shared__ __align__(16) char xsm[65536];
    const int t  = threadIdx.x;
    const int w  = t >> 6, l = t & 63;
    const int lq = l & 31, h = l >> 5;
    const int b  = blockIdx.x >> 6;
    const int n0 = (blockIdx.x & 63) << 6;

    {
        const int nq = t & 15;
#pragma unroll
        for (int i = 0; i < 2; i++) {
            int oct = (t >> 4) + 16 * i;
            const float* xp = x + ((size_t)b * CC + oct * 8) * NN + n0 + nq * 4;
            float4 r[8];
#pragma unroll
            for (int j = 0; j < 8; j++) r[j] = *(const float4*)(xp + (size_t)j * NN);
#pragma unroll
            for (int k = 0; k < 4; k++) {
                int n = nq * 4 + k;
                float v[8];
#pragma unroll
                for (int j = 0; j < 8; j++) v[j] = ((const float*)&r[j])[k];
                uint hw[4], lw[4];
#pragma unroll
                for (int j = 0; j < 4; j++) {
                    ushort ha = bfbits(v[2 * j]), hc = bfbits(v[2 * j + 1]);
                    hw[j] = (uint)ha | ((uint)hc << 16);
                    lw[j] = pk2(v[2 * j] - bf2f(ha), v[2 * j + 1] - bf2f(hc));
                }
                int uu = oct ^ (n & 31);
                *(uint4*)(xsm + n * 512 + uu * 16) = make_uint4(hw[0], hw[1], hw[2], hw[3]);
                *(uint4*)(xsm + 32768 + n * 512 + uu * 16) = make_uint4(lw[0], lw[1], lw[2], lw[3]);
            }
        }
    }
    __syncthreads();

    const int wo16 = w * 32 + lq;
    f32x16 acc[3][2];
    {
        float bt = b_t[wo16], bp = b_p[wo16];
        acc[0][0] = (f32x16)bt; acc[0][1] = (f32x16)bt;
        acc[1][0] = (f32x16)bp; acc[1][1] = (f32x16)bp;
        acc[2][0] = (f32x16)0.0f; acc[2][1] = (f32x16)0.0f;
    }

#pragma unroll 2
    for (int cs = 0; cs < 16; cs++) {
        int wi = (cs * 2 + h) * 128 + wo16;
        bf16x8 fth = asbf8(wt_h[wi]), ftl = asbf8(wt_l[wi]);
        bf16x8 fph = asbf8(wp_h[wi]), fpl = asbf8(wp_l[wi]);
        bf16x8 fgh = asbf8(wg_h[wi]), fgl = asbf8(wg_l[wi]);
        int xoff = lq * 512 + 16 * ((cs * 2 + h) ^ lq);
        bf16x8 xh0 = asbf8(*(const uint4*)(xsm + xoff));
        bf16x8 xh1 = asbf8(*(const uint4*)(xsm + 16384 + xoff));
        bf16x8 xl0 = asbf8(*(const uint4*)(xsm + 32768 + xoff));
        bf16x8 xl1 = asbf8(*(const uint4*)(xsm + 49152 + xoff));

        acc[0][0] = __builtin_amdgcn_mfma_f32_32x32x16_bf16(xh0, fth, acc[0][0], 0, 0, 0);
        acc[0][0] = __builtin_amdgcn_mfma_f32_32x32x16_bf16(xl0, fth, acc[0][0], 0, 0, 0);
        acc[0][0] = __builtin_amdgcn_mfma_f32_32x32x16_bf16(xh0, ftl, acc[0][0], 0, 0, 0);
        acc[0][1] = __builtin_amdgcn_mfma_f32_32x32x16_bf16(xh1, fth, acc[0][1], 0, 0, 0);
        acc[0][1] = __builtin_amdgcn_mfma_f32_32x32x16_bf16(xl1, fth, acc[0][1], 0, 0, 0);
        acc[0][1] = __builtin_amdgcn_mfma_f32_32x32x16_bf16(xh1, ftl, acc[0][1], 0, 0, 0);

        acc[1][0] = __builtin_amdgcn_mfma_f32_32x32x16_bf16(xh0, fph, acc[1][0], 0, 0, 0);
        acc[1][0] = __builtin_amdgcn_mfma_f32_32x32x16_bf16(xl0, fph, acc[1][0], 0, 0, 0);
        acc[1][0] = __builtin_amdgcn_mfma_f32_32x32x16_bf16(xh0, fpl, acc[1][0], 0, 0, 0);
        acc[1][1] = __builtin_amdgcn_mfma_f32_32x32x16_bf16(xh1, fph, acc[1][1], 0, 0, 0);
        acc[1][1] = __builtin_amdgcn_mfma_f32_32x32x16_bf16(xl1, fph, acc[1][1], 0, 0, 0);
        acc[1][1] = __builtin_amdgcn_mfma_f32_32x32x16_bf16(xh1, fpl, acc[1][1], 0, 0, 0);

        acc[2][0] = __builtin_amdgcn_mfma_f32_32x32x16_bf16(fgh, xh0, acc[2][0], 0, 0, 0);
        acc[2][0] = __builtin_amdgcn_mfma_f32_32x32x16_bf16(fgh, xl0, acc[2][0], 0, 0, 0);
        acc[2][0] = __builtin_amdgcn_mfma_f32_32x32x16_bf16(fgl, xh0, acc[2][0], 0, 0, 0);
        acc[2][1] = __builtin_amdgcn_mfma_f32_32x32x16_bf16(fgh, xh1, acc[2][1], 0, 0, 0);
        acc[2][1] = __builtin_amdgcn_mfma_f32_32x32x16_bf16(fgh, xl1, acc[2][1], 0, 0, 0);
        acc[2][1] = __builtin_amdgcn_mfma_f32_32x32x16_bf16(fgl, xh1, acc[2][1], 0, 0, 0);
    }

#pragma unroll
    for (int ns = 0; ns < 2; ns++) {
        size_t nb = (size_t)b * NN + n0 + ns * 32;
#pragma unroll
        for (int r = 0; r < 16; r++) {
            int nr = (r & 3) + 8 * (r >> 2) + 4 * h;
            size_t idx = (nb + nr) * CI + wo16;
            th[idx]  = hbits(acc[0][ns][r] * LOG2E);   // exp2-domain fp16 theta
            phi[idx] = hbits(acc[1][ns][r]);           // fp16 phi
        }
#pragma unroll
        for (int r = 0; r < 16; r++) {
            int orow = w * 32 + (r & 3) + 8 * (r >> 2) + 4 * h;
            gT[((size_t)b * CI + orow) * NN + n0 + ns * 32 + lq] =
                bfbits(acc[2][ns][r] + b_g[orow]);
        }
    }
}

// ---------------------------------------------------------------------------
// Kernel 2: MFMA flash attention, grid-level k-split (R11 verbatim, proven
// 90.6 us). grid = 512 x 256 (4 waves): b = blk&7 (XCD affinity),
// qt = (blk>>3)&31, kt = blk>>8 (k half). 64 KB LDS -> 2 independent
// blocks/CU. Serial QK->softmax->PV, relaxed vmcnt(8), fixed-max
// exp2(s-88) softmax, permlane P-redistribution. Epilogue: NORMALIZED
// per-half bf16 y + per-row l.
// ---------------------------------------------------------------------------
__global__ __launch_bounds__(256, 2) void attn_mfma(
    const ushort* __restrict__ th, const ushort* __restrict__ phi,
    const ushort* __restrict__ gT,
    ushort* __restrict__ yP, float* __restrict__ lP)
{
    __shared__ __align__(16) char sm[65536];
    const int t  = threadIdx.x;
    const int w  = t >> 6, l = t & 63;
    const int lq = l & 31, h = l >> 5;
    const int b  = blockIdx.x & 7;
    const int qt = (blockIdx.x >> 3) & 31;
    const int kt = blockIdx.x >> 8;
    const int q0 = qt * 128 + w * 32;

    f16x8 thf[8];
    {
        const char* thp = (const char*)(th + ((size_t)b * NN + q0 + lq) * CI);
#pragma unroll
        for (int cs = 0; cs < 8; cs++)
            thf[cs] = __builtin_bit_cast(f16x8, *(const uint4*)(thp + cs * 32 + h * 16));
    }

    const char* phig = (const char*)(phi + (size_t)b * NN * CI);
    const char* gTg  = (const char*)(gT + (size_t)b * NN * CI);

    f32x16 ya[4];
#pragma unroll
    for (int ct = 0; ct < 4; ct++) ya[ct] = (f32x16)0.0f;
    float l_run = 0.0f;

    auto stage = [&](int buf, int tile) {   // tile = global k-tile index
        const char* ps = phig + (size_t)tile * 16384;
        const char* gs = gTg + (size_t)tile * 128;
        char* lb = sm + buf * 32768;
#pragma unroll
        for (int j = 0; j < 4; j++) {
            int c  = w * 4 + j;
            int r  = c * 4 + (l >> 4);
            int cp = ((l & 15) * 16) ^ ((r & 15) << 4);
            gload16(ps + (size_t)r * 256 + cp, lb + c * 1024);
            int r8 = c * 8 + (l >> 3);
            int cg = ((l & 7) * 16) ^ ((r8 & 7) << 4);
            gload16(gs + (size_t)r8 * (NN * 2) + cg, lb + 16384 + c * 1024);
        }
    };

    const int t0 = kt * 32;
    stage(0, t0 + 0);
    stage(1, t0 + 1);
    asm volatile("s_waitcnt vmcnt(8)" ::: "memory");
    __builtin_amdgcn_s_barrier();
    __builtin_amdgcn_sched_barrier(0);

    const int swp = (lq & 15) << 4;
    const int swg = (lq & 7) << 4;

    for (int it = 0; it < 32; it++) {
        const char* smb = sm + (it & 1) * 32768;

        // ---- QK^T: fp16 single-precision, 2 independent 8-deep chains ----
        f32x16 sa0 = (f32x16)0.0f, sa1 = (f32x16)0.0f;
        __builtin_amdgcn_s_setprio(1);
#pragma unroll
        for (int cs = 0; cs < 8; cs++) {
            f16x8 f0 = __builtin_bit_cast(f16x8,
                *(const uint4*)(smb + lq * 256 + ((cs * 32 + h * 16) ^ swp)));
            f16x8 f1 = __builtin_bit_cast(f16x8,
                *(const uint4*)(smb + (32 + lq) * 256 + ((cs * 32 + h * 16) ^ swp)));
            sa0 = __builtin_amdgcn_mfma_f32_32x32x16_f16(f0, thf[cs], sa0, 0, 0, 0);
            sa1 = __builtin_amdgcn_mfma_f32_32x32x16_f16(f1, thf[cs], sa1, 0, 0, 0);
        }
        __builtin_amdgcn_s_setprio(0);

        // ---- fixed-max softmax in place: P = exp2(S - 88) ----
        {
            float t0s = 0.f, t1s = 0.f, t2s = 0.f, t3s = 0.f;
#pragma unroll
            for (int r = 0; r < 16; r += 4) {
                sa0[r]     = fexp2(sa0[r] - FIXMAX);     t0s += sa0[r];
                sa0[r + 1] = fexp2(sa0[r + 1] - FIXMAX); t1s += sa0[r + 1];
                sa0[r + 2] = fexp2(sa0[r + 2] - FIXMAX); t2s += sa0[r + 2];
                sa0[r + 3] = fexp2(sa0[r + 3] - FIXMAX); t3s += sa0[r + 3];
            }
#pragma unroll
            for (int r = 0; r < 16; r += 4) {
                sa1[r]     = fexp2(sa1[r] - FIXMAX);     t0s += sa1[r];
                sa1[r + 1] = fexp2(sa1[r + 1] - FIXMAX); t1s += sa1[r + 1];
                sa1[r + 2] = fexp2(sa1[r + 2] - FIXMAX); t2s += sa1[r + 2];
                sa1[r + 3] = fexp2(sa1[r + 3] - FIXMAX); t3s += sa1[r + 3];
            }
            l_run += (t0s + t1s) + (t2s + t3s);
        }

        // ---- PV: Y^T += gT_tile * P^T (bf16 P via permlane32_swap) ----
        __builtin_amdgcn_s_setprio(1);
#pragma unroll
        for (int mt = 0; mt < 2; mt++) {
            const f32x16& pa = mt ? sa1 : sa0;
#pragma unroll
            for (int s = 0; s < 2; s++) {
                const int base = s * 8;
                uint a0 = pk2(pa[base + 0], pa[base + 1]);
                uint a1 = pk2(pa[base + 2], pa[base + 3]);
                uint b0 = pk2(pa[base + 4], pa[base + 5]);
                uint b1 = pk2(pa[base + 6], pa[base + 7]);
                asm volatile("v_permlane32_swap_b32 %0, %1" : "+v"(a0), "+v"(b0));
                asm volatile("v_permlane32_swap_b32 %0, %1" : "+v"(a1), "+v"(b1));
                bf16x8 pf = __builtin_bit_cast(bf16x8, make_uint4(a0, a1, b0, b1));
                const int ks = mt * 2 + s;
#pragma unroll
                for (int ct = 0; ct < 4; ct++) {
                    bf16x8 gf = __builtin_bit_cast(bf16x8,
                        *(const uint4*)(smb + 16384 + (ct * 32 + lq) * 128 +
                                        ((ks * 32 + h * 16) ^ swg)));
                    ya[ct] = __builtin_amdgcn_mfma_f32_32x32x16_bf16(gf, pf, ya[ct], 0, 0, 0);
                }
            }
        }
        __builtin_amdgcn_s_setprio(0);

        // ---- pipeline maintenance: relaxed counted vmcnt ----
        asm volatile("" ::: "memory");
        __builtin_amdgcn_s_barrier();                  // done reading smb
        if (it < 30) {
            stage(it & 1, t0 + it + 2);
            asm volatile("s_waitcnt vmcnt(8)" ::: "memory");  // tile it+1 landed
            __builtin_amdgcn_s_barrier();
            __builtin_amdgcn_sched_barrier(0);
        } else if (it == 30) {
            asm volatile("s_waitcnt vmcnt(0)" ::: "memory");  // tile 31 landed
            __builtin_amdgcn_s_barrier();
            __builtin_amdgcn_sched_barrier(0);
        }
    }

    // ---- epilogue: NORMALIZED per-half bf16 y + per-row l ----
    float ltot = l_run + __shfl_xor(l_run, 32);
    if (h == 0) lP[((size_t)kt * 8 + b) * NN + q0 + lq] = ltot;
    float inv = 1.0f / ltot;

    ushort* yp = yP + (size_t)kt * ((size_t)BB * NN * CI);
    const size_t qb = ((size_t)b * NN + q0 + lq) * CI;
#pragma unroll
    for (int ct = 0; ct < 4; ct++)
#pragma unroll
        for (int r4 = 0; r4 < 4; r4++) {
            uint2 hw = make_uint2(
                pk2(ya[ct][r4 * 4 + 0] * inv, ya[ct][r4 * 4 + 1] * inv),
                pk2(ya[ct][r4 * 4 + 2] * inv, ya[ct][r4 * 4 + 3] * inv));
            int co = 32 * ct + 8 * r4 + 4 * h;
            *(uint2*)(yp + qb + co) = hw;
        }
}

// ---------------------------------------------------------------------------
// Kernel 3: merged out-projection with LDS pre-combine. Stages BOTH
// normalized k-half results (R12-proven staging), then combines IN LDS:
// yC[n][ci] = bf16(aA[n]*yA + aB[n]*yB) with aA = lA/(lA+lB) (the proven
// R11 ymerge formula, relocated). The GEMM then runs on yC only — half the
// MFMAs and half the LDS reads of R14. Epilogue: BN + residual.
// ---------------------------------------------------------------------------
__global__ __launch_bounds__(256, 2) void outproj_mfma(
    const ushort* __restrict__ yP, const float* __restrict__ lP,
    const uint4* __restrict__ wo_h, const uint4* __restrict__ wo_l,
    const float* __restrict__ scale, const float* __restrict__ shift,
    const float* __restrict__ x, float* __restrict__ out)
{
    __shared__ __align__(16) char ysm[32768];
    const int t  = threadIdx.x;
    const int w  = t >> 6, l = t & 63;
    const int lq = l & 31, h = l >> 5;
    const int b  = blockIdx.x >> 6;
    const int n0 = (blockIdx.x & 63) << 6;
    const size_t arr = (size_t)BB * NN * CI;

    // ---- stage yA -> [0,16K), yB -> [16K,32K) (R12-proven layout) ----
    {
#pragma unroll
        for (int j = 0; j < 4; j++) {
            int idx = w * 64 + j * 256 + l;
            int row = idx >> 4, u = idx & 15;
            size_t srow = ((size_t)b * NN + n0 + row) * CI;
            int cb = 16 * (u ^ (row & 15));
            gload16((const char*)yP + srow * 2 + cb, ysm + (w * 64 + j * 256) * 16);
            gload16((const char*)(yP + arr) + srow * 2 + cb,
                    ysm + 16384 + (w * 64 + j * 256) * 16);
        }
    }
    __syncthreads();

    // ---- pre-combine: ysm[0,16K) = bf16(aA*yA + aB*yB), unit-wise ----
    // yA[idx] and yB[idx] hold the SAME global unit (same cb swizzle), so
    // the combine is element-aligned. Each thread owns 4 of the 1024 units.
    {
#pragma unroll
        for (int j = 0; j < 4; j++) {
            int idx = j * 256 + t;
            int row = idx >> 4;
            int n = n0 + row;
            float lA = lP[(size_t)b * NN + n];
            float lB = lP[(size_t)(8 + b) * NN + n];
            float s = 1.0f / (lA + lB);
            float aA = lA * s, aB = lB * s;
            uint4 va = *(const uint4*)(ysm + idx * 16);
            uint4 vb = *(const uint4*)(ysm + 16384 + idx * 16);
            const uint* pa = (const uint*)&va;
            const uint* pb = (const uint*)&vb;
            uint ho[4];
#pragma unroll
            for (int k = 0; k < 4; k++) {
                float v0 = aA * bflo(pa[k]) + aB * bflo(pb[k]);
                float v1 = aA * bfhi(pa[k]) + aB * bfhi(pb[k]);
                ho[k] = pk2(v0, v1);
            }
            *(uint4*)(ysm + idx * 16) = make_uint4(ho[0], ho[1], ho[2], ho[3]);
        }
    }
    __syncthreads();

    // ---- GEMM on combined y: half the MFMAs of the 2-partial version ----
#pragma unroll
    for (int oi = 0; oi < 2; oi++) {
        const int ot = w + oi * 4;
        const int ob = ot * 32 + lq;
        f32x16 c0 = (f32x16)0.0f, c1 = (f32x16)0.0f;
#pragma unroll 2
        for (int cs = 0; cs < 8; cs++) {
            int wi = (cs * 2 + h) * 256 + ob;
            bf16x8 wfh = asbf8(wo_h[wi]), wfl = asbf8(wo_l[wi]);
            int xoff = lq * 256 + 16 * ((cs * 2 + h) ^ (lq & 15));
            bf16x8 y0 = asbf8(*(const uint4*)(ysm + xoff));
            bf16x8 y1 = asbf8(*(const uint4*)(ysm + 8192 + xoff));
            c0 = __builtin_amdgcn_mfma_f32_32x32x16_bf16(wfh, y0, c0, 0, 0, 0);
            c0 = __builtin_amdgcn_mfma_f32_32x32x16_bf16(wfl, y0, c0, 0, 0, 0);
            c1 = __builtin_amdgcn_mfma_f32_32x32x16_bf16(wfh, y1, c1, 0, 0, 0);
            c1 = __builtin_amdgcn_mfma_f32_32x32x16_bf16(wfl, y1, c1, 0, 0, 0);
        }
#pragma unroll
        for (int ns = 0; ns < 2; ns++) {
            const f32x16& av = ns ? c1 : c0;
#pragma unroll
            for (int r = 0; r < 16; r++) {
                int o = ot * 32 + (r & 3) + 8 * (r >> 2) + 4 * h;
                size_t ai = ((size_t)b * CC + o) * NN + n0 + ns * 32 + lq;
                out[ai] = av[r] * scale[o] + shift[o] + x[ai];
            }
        }
    }
}

extern "C" void kernel_launch(void* const* d_in, const int* in_sizes, int n_in,
                              void* d_out, int out_size, void* d_ws, size_t ws_size,
                              hipStream_t stream) {
    const float* x       = (const float*)d_in[0];
    const float* w_g     = (const float*)d_in[1];
    const float* b_g     = (const float*)d_in[2];
    const float* w_theta = (const float*)d_in[3];
    const float* b_theta = (const float*)d_in[4];
    const float* w_phi   = (const float*)d_in[5];
    const float* b_phi   = (const float*)d_in[6];
    const float* w_out   = (const float*)d_in[7];
    const float* b_out   = (const float*)d_in[8];
    const float* bn_g    = (const float*)d_in[9];
    const float* bn_b    = (const float*)d_in[10];
    const float* bn_m    = (const float*)d_in[11];
    const float* bn_v    = (const float*)d_in[12];
    float* out = (float*)d_out;

    const size_t arr = (size_t)BB * NN * CI;
    ushort* thw   = (ushort*)d_ws;                  // fp16 theta,      8 MiB
    ushort* phiw  = thw + arr;                      // fp16 phi,        8 MiB
    ushort* gTw   = phiw + arr;                     // bf16 gT,         8 MiB
    ushort* yPb   = gTw + arr;                      // bf16 y halves,  16 MiB
    uint4*  wt_h  = (uint4*)(yPb + 2 * arr);
    uint4*  wt_l  = wt_h + 4096;
    uint4*  wp_h  = wt_l + 4096;
    uint4*  wp_l  = wp_h + 4096;
    uint4*  wg_h  = wp_l + 4096;
    uint4*  wg_l  = wg_h + 4096;
    uint4*  wo_h  = wg_l + 4096;
    uint4*  wo_l  = wo_h + 4096;
    float*  scl   = (float*)(wo_l + 4096);
    float*  shf   = scl + 256;
    float*  lPb   = shf + 256;                      // l halves, 256 KiB

    wconv_kernel<<<65, 256, 0, stream>>>(
        w_theta, w_phi, w_g, w_out, bn_g, bn_b, bn_m, bn_v, b_out,
        wt_h, wt_l, wp_h, wp_l, wg_h, wg_l, wo_h, wo_l, scl, shf);
    proj3_mfma<<<BB * 64, 256, 0, stream>>>(
        x, wt_h, wt_l, wp_h, wp_l, wg_h, wg_l, b_theta, b_phi, b_g,
        thw, phiw, gTw);
    attn_mfma<<<512, 256, 0, stream>>>(thw, phiw, gTw, yPb, lPb);
    outproj_mfma<<<BB * 64, 256, 0, stream>>>(
        yPb, lPb, wo_h, wo_l, scl, shf, x, out);
}

// Round 18
// 138.870 us; speedup vs baseline: 1.0012x; 1.0012x over previous
//
#include <hip/hip_runtime.h>
#include <math.h>

#define BB 8
#define CC 256
#define CI 128
#define NN 4096
#define BN_EPS 1e-5f
#define LOG2E 1.4426950408889634f
#define FIXMAX 88.0f

typedef unsigned int uint;
typedef unsigned short ushort;
typedef __bf16 bf16x8 __attribute__((ext_vector_type(8)));
typedef _Float16 f16x8 __attribute__((ext_vector_type(8)));
typedef float f32x16 __attribute__((ext_vector_type(16)));

__device__ __forceinline__ ushort bfbits(float f) {
    return __builtin_bit_cast(ushort, (__bf16)f);
}
__device__ __forceinline__ ushort hbits(float f) {
    return __builtin_bit_cast(ushort, (_Float16)f);
}
__device__ __forceinline__ float bf2f(ushort h) {
    return __uint_as_float(((uint)h) << 16);
}
__device__ __forceinline__ float bflo(uint v) { return __uint_as_float(v << 16); }
__device__ __forceinline__ float bfhi(uint v) { return __uint_as_float(v & 0xffff0000u); }
__device__ __forceinline__ uint pk2(float a, float b) {
    return (uint)bfbits(a) | ((uint)bfbits(b) << 16);
}
__device__ __forceinline__ void gload16(const void* g, void* l) {
    __builtin_amdgcn_global_load_lds(
        (const __attribute__((address_space(1))) uint*)g,
        (__attribute__((address_space(3))) uint*)l, 16, 0, 0);
}
__device__ __forceinline__ bf16x8 asbf8(uint4 v) { return __builtin_bit_cast(bf16x8, v); }
__device__ __forceinline__ float fexp2(float a) {
    float e;
    asm("v_exp_f32 %0, %1" : "=v"(e) : "v"(a));
    return e;
}

// ---------------------------------------------------------------------------
// Kernel 0: weight conversion to split-bf16, fragment-major [cs][h][o].
// ---------------------------------------------------------------------------
__global__ __launch_bounds__(256) void wconv_kernel(
    const float* __restrict__ w_t, const float* __restrict__ w_p,
    const float* __restrict__ w_g, const float* __restrict__ w_o,
    const float* __restrict__ bn_g, const float* __restrict__ bn_b,
    const float* __restrict__ bn_m, const float* __restrict__ bn_v,
    const float* __restrict__ b_out,
    uint4* __restrict__ wt_h, uint4* __restrict__ wt_l,
    uint4* __restrict__ wp_h, uint4* __restrict__ wp_l,
    uint4* __restrict__ wg_h, uint4* __restrict__ wg_l,
    uint4* __restrict__ wo_h, uint4* __restrict__ wo_l,
    float* __restrict__ scale, float* __restrict__ shift)
{
    const int t = threadIdx.x, blk = blockIdx.x;
    if (blk == 64) {
        float inv = bn_g[t] * rsqrtf(bn_v[t] + BN_EPS);
        scale[t] = inv;
        shift[t] = b_out[t] * inv + bn_b[t] - bn_m[t] * inv;
        return;
    }
    int u = blk * 256 + t;
    int mat = u >> 12, ul = u & 4095;
    const float* src;
    uint4 *dh, *dl;
    int o, oct, C, O;
    if (mat == 0)      { src = w_t; dh = wt_h; dl = wt_l; }
    else if (mat == 1) { src = w_p; dh = wp_h; dl = wp_l; }
    else if (mat == 2) { src = w_g; dh = wg_h; dl = wg_l; }
    else               { src = w_o; dh = wo_h; dl = wo_l; }
    if (mat < 3) { O = 128; C = 256; o = ul >> 5; oct = ul & 31; }
    else         { O = 256; C = 128; o = ul >> 4; oct = ul & 15; }
    const float* s = src + (size_t)o * C + oct * 8;
    float4 va = *(const float4*)s, vb = *(const float4*)(s + 4);
    float v[8] = {va.x, va.y, va.z, va.w, vb.x, vb.y, vb.z, vb.w};
    uint hw[4], lw[4];
#pragma unroll
    for (int j = 0; j < 4; j++) {
        float a = v[2 * j], c = v[2 * j + 1];
        ushort ha = bfbits(a), hc = bfbits(c);
        hw[j] = (uint)ha | ((uint)hc << 16);
        lw[j] = pk2(a - bf2f(ha), c - bf2f(hc));
    }
    int di = oct * O + o;
    dh[di] = make_uint4(hw[0], hw[1], hw[2], hw[3]);
    dl[di] = make_uint4(lw[0], lw[1], lw[2], lw[3]);
}

// ---------------------------------------------------------------------------
// Kernel 1: fused theta/phi/g projections via MFMA (3-term split-bf16 ==
// ~f32 accuracy internally). theta/phi stored FP16 (exp2-domain theta) for
// the fp16 QK MFMA; g stored transposed bf16 for the PV MFMA.
// ---------------------------------------------------------------------------
__global__ __launch_bounds__(256, 2) void proj3_mfma(
    const float* __restrict__ x,
    const uint4* __restrict__ wt_h, const uint4* __restrict__ wt_l,
    const uint4* __restrict__ wp_h, const uint4* __restrict__ wp_l,
    const uint4* __restrict__ wg_h, const uint4* __restrict__ wg_l,
    const float* __restrict__ b_t, const float* __restrict__ b_p,
    const float* __restrict__ b_g,
    ushort* __restrict__ th, ushort* __restrict__ phi, ushort* __restrict__ gT)
{
    __shared__ __align__(16) char xsm[65536];
    const int t  = threadIdx.x;
    const int w  = t >> 6, l = t & 63;
    const int lq = l & 31, h = l >> 5;
    const int b  = blockIdx.x >> 6;
    const int n0 = (blockIdx.x & 63) << 6;

    {
        const int nq = t & 15;
#pragma unroll
        for (int i = 0; i < 2; i++) {
            int oct = (t >> 4) + 16 * i;
            const float* xp = x + ((size_t)b * CC + oct * 8) * NN + n0 + nq * 4;
            float4 r[8];
#pragma unroll
            for (int j = 0; j < 8; j++) r[j] = *(const float4*)(xp + (size_t)j * NN);
#pragma unroll
            for (int k = 0; k < 4; k++) {
                int n = nq * 4 + k;
                float v[8];
#pragma unroll
                for (int j = 0; j < 8; j++) v[j] = ((const float*)&r[j])[k];
                uint hw[4], lw[4];
#pragma unroll
                for (int j = 0; j < 4; j++) {
                    ushort ha = bfbits(v[2 * j]), hc = bfbits(v[2 * j + 1]);
                    hw[j] = (uint)ha | ((uint)hc << 16);
                    lw[j] = pk2(v[2 * j] - bf2f(ha), v[2 * j + 1] - bf2f(hc));
                }
                int uu = oct ^ (n & 31);
                *(uint4*)(xsm + n * 512 + uu * 16) = make_uint4(hw[0], hw[1], hw[2], hw[3]);
                *(uint4*)(xsm + 32768 + n * 512 + uu * 16) = make_uint4(lw[0], lw[1], lw[2], lw[3]);
            }
        }
    }
    __syncthreads();

    const int wo16 = w * 32 + lq;
    f32x16 acc[3][2];
    {
        float bt = b_t[wo16], bp = b_p[wo16];
        acc[0][0] = (f32x16)bt; acc[0][1] = (f32x16)bt;
        acc[1][0] = (f32x16)bp; acc[1][1] = (f32x16)bp;
        acc[2][0] = (f32x16)0.0f; acc[2][1] = (f32x16)0.0f;
    }

#pragma unroll 2
    for (int cs = 0; cs < 16; cs++) {
        int wi = (cs * 2 + h) * 128 + wo16;
        bf16x8 fth = asbf8(wt_h[wi]), ftl = asbf8(wt_l[wi]);
        bf16x8 fph = asbf8(wp_h[wi]), fpl = asbf8(wp_l[wi]);
        bf16x8 fgh = asbf8(wg_h[wi]), fgl = asbf8(wg_l[wi]);
        int xoff = lq * 512 + 16 * ((cs * 2 + h) ^ lq);
        bf16x8 xh0 = asbf8(*(const uint4*)(xsm + xoff));
        bf16x8 xh1 = asbf8(*(const uint4*)(xsm + 16384 + xoff));
        bf16x8 xl0 = asbf8(*(const uint4*)(xsm + 32768 + xoff));
        bf16x8 xl1 = asbf8(*(const uint4*)(xsm + 49152 + xoff));

        acc[0][0] = __builtin_amdgcn_mfma_f32_32x32x16_bf16(xh0, fth, acc[0][0], 0, 0, 0);
        acc[0][0] = __builtin_amdgcn_mfma_f32_32x32x16_bf16(xl0, fth, acc[0][0], 0, 0, 0);
        acc[0][0] = __builtin_amdgcn_mfma_f32_32x32x16_bf16(xh0, ftl, acc[0][0], 0, 0, 0);
        acc[0][1] = __builtin_amdgcn_mfma_f32_32x32x16_bf16(xh1, fth, acc[0][1], 0, 0, 0);
        acc[0][1] = __builtin_amdgcn_mfma_f32_32x32x16_bf16(xl1, fth, acc[0][1], 0, 0, 0);
        acc[0][1] = __builtin_amdgcn_mfma_f32_32x32x16_bf16(xh1, ftl, acc[0][1], 0, 0, 0);

        acc[1][0] = __builtin_amdgcn_mfma_f32_32x32x16_bf16(xh0, fph, acc[1][0], 0, 0, 0);
        acc[1][0] = __builtin_amdgcn_mfma_f32_32x32x16_bf16(xl0, fph, acc[1][0], 0, 0, 0);
        acc[1][0] = __builtin_amdgcn_mfma_f32_32x32x16_bf16(xh0, fpl, acc[1][0], 0, 0, 0);
        acc[1][1] = __builtin_amdgcn_mfma_f32_32x32x16_bf16(xh1, fph, acc[1][1], 0, 0, 0);
        acc[1][1] = __builtin_amdgcn_mfma_f32_32x32x16_bf16(xl1, fph, acc[1][1], 0, 0, 0);
        acc[1][1] = __builtin_amdgcn_mfma_f32_32x32x16_bf16(xh1, fpl, acc[1][1], 0, 0, 0);

        acc[2][0] = __builtin_amdgcn_mfma_f32_32x32x16_bf16(fgh, xh0, acc[2][0], 0, 0, 0);
        acc[2][0] = __builtin_amdgcn_mfma_f32_32x32x16_bf16(fgh, xl0, acc[2][0], 0, 0, 0);
        acc[2][0] = __builtin_amdgcn_mfma_f32_32x32x16_bf16(fgl, xh0, acc[2][0], 0, 0, 0);
        acc[2][1] = __builtin_amdgcn_mfma_f32_32x32x16_bf16(fgh, xh1, acc[2][1], 0, 0, 0);
        acc[2][1] = __builtin_amdgcn_mfma_f32_32x32x16_bf16(fgh, xl1, acc[2][1], 0, 0, 0);
        acc[2][1] = __builtin_amdgcn_mfma_f32_32x32x16_bf16(fgl, xh1, acc[2][1], 0, 0, 0);
    }

#pragma unroll
    for (int ns = 0; ns < 2; ns++) {
        size_t nb = (size_t)b * NN + n0 + ns * 32;
#pragma unroll
        for (int r = 0; r < 16; r++) {
            int nr = (r & 3) + 8 * (r >> 2) + 4 * h;
            size_t idx = (nb + nr) * CI + wo16;
            th[idx]  = hbits(acc[0][ns][r] * LOG2E);   // exp2-domain fp16 theta
            phi[idx] = hbits(acc[1][ns][r]);           // fp16 phi
        }
#pragma unroll
        for (int r = 0; r < 16; r++) {
            int orow = w * 32 + (r & 3) + 8 * (r >> 2) + 4 * h;
            gT[((size_t)b * CI + orow) * NN + n0 + ns * 32 + lq] =
                bfbits(acc[2][ns][r] + b_g[orow]);
        }
    }
}

// ---------------------------------------------------------------------------
// Kernel 2: MFMA flash attention, grid-level k-split (proven 90.6 us).
// grid = 512 x 256 (4 waves): b = blk&7 (XCD affinity), qt = (blk>>3)&31,
// kt = blk>>8 (k half). 64 KB LDS -> 2 independent blocks/CU. Serial
// QK->softmax->PV, relaxed vmcnt(8), fixed-max exp2(s-88) softmax (the
// explicit subtract is REQUIRED: inline-asm v_exp_f32 must not read the
// MFMA accumulator directly -- MFMA->asm hazard, broke R10/R16/R17),
// permlane P-redistribution. Epilogue: NORMALIZED per-half bf16 y + l.
// ---------------------------------------------------------------------------
__global__ __launch_bounds__(256, 2) void attn_mfma(
    const ushort* __restrict__ th, const ushort* __restrict__ phi,
    const ushort* __restrict__ gT,
    ushort* __restrict__ yP, float* __restrict__ lP)
{
    __shared__ __align__(16) char sm[65536];
    const int t  = threadIdx.x;
    const int w  = t >> 6, l = t & 63;
    const int lq = l & 31, h = l >> 5;
    const int b  = blockIdx.x & 7;
    const int qt = (blockIdx.x >> 3) & 31;
    const int kt = blockIdx.x >> 8;
    const int q0 = qt * 128 + w * 32;

    f16x8 thf[8];
    {
        const char* thp = (const char*)(th + ((size_t)b * NN + q0 + lq) * CI);
#pragma unroll
        for (int cs = 0; cs < 8; cs++)
            thf[cs] = __builtin_bit_cast(f16x8, *(const uint4*)(thp + cs * 32 + h * 16));
    }

    const char* phig = (const char*)(phi + (size_t)b * NN * CI);
    const char* gTg  = (const char*)(gT + (size_t)b * NN * CI);

    f32x16 ya[4];
#pragma unroll
    for (int ct = 0; ct < 4; ct++) ya[ct] = (f32x16)0.0f;
    float l_run = 0.0f;

    auto stage = [&](int buf, int tile) {   // tile = global k-tile index
        const char* ps = phig + (size_t)tile * 16384;
        const char* gs = gTg + (size_t)tile * 128;
        char* lb = sm + buf * 32768;
#pragma unroll
        for (int j = 0; j < 4; j++) {
            int c  = w * 4 + j;
            int r  = c * 4 + (l >> 4);
            int cp = ((l & 15) * 16) ^ ((r & 15) << 4);
            gload16(ps + (size_t)r * 256 + cp, lb + c * 1024);
            int r8 = c * 8 + (l >> 3);
            int cg = ((l & 7) * 16) ^ ((r8 & 7) << 4);
            gload16(gs + (size_t)r8 * (NN * 2) + cg, lb + 16384 + c * 1024);
        }
    };

    const int t0 = kt * 32;
    stage(0, t0 + 0);
    stage(1, t0 + 1);
    asm volatile("s_waitcnt vmcnt(8)" ::: "memory");
    __builtin_amdgcn_s_barrier();
    __builtin_amdgcn_sched_barrier(0);

    const int swp = (lq & 15) << 4;
    const int swg = (lq & 7) << 4;

    for (int it = 0; it < 32; it++) {
        const char* smb = sm + (it & 1) * 32768;

        // ---- QK^T: fp16 single-precision, 2 independent 8-deep chains ----
        f32x16 sa0 = (f32x16)0.0f, sa1 = (f32x16)0.0f;
        __builtin_amdgcn_s_setprio(1);
#pragma unroll
        for (int cs = 0; cs < 8; cs++) {
            f16x8 f0 = __builtin_bit_cast(f16x8,
                *(const uint4*)(smb + lq * 256 + ((cs * 32 + h * 16) ^ swp)));
            f16x8 f1 = __builtin_bit_cast(f16x8,
                *(const uint4*)(smb + (32 + lq) * 256 + ((cs * 32 + h * 16) ^ swp)));
            sa0 = __builtin_amdgcn_mfma_f32_32x32x16_f16(f0, thf[cs], sa0, 0, 0, 0);
            sa1 = __builtin_amdgcn_mfma_f32_32x32x16_f16(f1, thf[cs], sa1, 0, 0, 0);
        }
        __builtin_amdgcn_s_setprio(0);

        // ---- fixed-max softmax in place: P = exp2(S - 88) ----
        {
            float t0s = 0.f, t1s = 0.f, t2s = 0.f, t3s = 0.f;
#pragma unroll
            for (int r = 0; r < 16; r += 4) {
                sa0[r]     = fexp2(sa0[r] - FIXMAX);     t0s += sa0[r];
                sa0[r + 1] = fexp2(sa0[r + 1] - FIXMAX); t1s += sa0[r + 1];
                sa0[r + 2] = fexp2(sa0[r + 2] - FIXMAX); t2s += sa0[r + 2];
                sa0[r + 3] = fexp2(sa0[r + 3] - FIXMAX); t3s += sa0[r + 3];
            }
#pragma unroll
            for (int r = 0; r < 16; r += 4) {
                sa1[r]     = fexp2(sa1[r] - FIXMAX);     t0s += sa1[r];
                sa1[r + 1] = fexp2(sa1[r + 1] - FIXMAX); t1s += sa1[r + 1];
                sa1[r + 2] = fexp2(sa1[r + 2] - FIXMAX); t2s += sa1[r + 2];
                sa1[r + 3] = fexp2(sa1[r + 3] - FIXMAX); t3s += sa1[r + 3];
            }
            l_run += (t0s + t1s) + (t2s + t3s);
        }

        // ---- PV: Y^T += gT_tile * P^T (bf16 P via permlane32_swap) ----
        __builtin_amdgcn_s_setprio(1);
#pragma unroll
        for (int mt = 0; mt < 2; mt++) {
            const f32x16& pa = mt ? sa1 : sa0;
#pragma unroll
            for (int s = 0; s < 2; s++) {
                const int base = s * 8;
                uint a0 = pk2(pa[base + 0], pa[base + 1]);
                uint a1 = pk2(pa[base + 2], pa[base + 3]);
                uint b0 = pk2(pa[base + 4], pa[base + 5]);
                uint b1 = pk2(pa[base + 6], pa[base + 7]);
                asm volatile("v_permlane32_swap_b32 %0, %1" : "+v"(a0), "+v"(b0));
                asm volatile("v_permlane32_swap_b32 %0, %1" : "+v"(a1), "+v"(b1));
                bf16x8 pf = __builtin_bit_cast(bf16x8, make_uint4(a0, a1, b0, b1));
                const int ks = mt * 2 + s;
#pragma unroll
                for (int ct = 0; ct < 4; ct++) {
                    bf16x8 gf = __builtin_bit_cast(bf16x8,
                        *(const uint4*)(smb + 16384 + (ct * 32 + lq) * 128 +
                                        ((ks * 32 + h * 16) ^ swg)));
                    ya[ct] = __builtin_amdgcn_mfma_f32_32x32x16_bf16(gf, pf, ya[ct], 0, 0, 0);
                }
            }
        }
        __builtin_amdgcn_s_setprio(0);

        // ---- pipeline maintenance: relaxed counted vmcnt ----
        asm volatile("" ::: "memory");
        __builtin_amdgcn_s_barrier();                  // done reading smb
        if (it < 30) {
            stage(it & 1, t0 + it + 2);
            asm volatile("s_waitcnt vmcnt(8)" ::: "memory");  // tile it+1 landed
            __builtin_amdgcn_s_barrier();
            __builtin_amdgcn_sched_barrier(0);
        } else if (it == 30) {
            asm volatile("s_waitcnt vmcnt(0)" ::: "memory");  // tile 31 landed
            __builtin_amdgcn_s_barrier();
            __builtin_amdgcn_sched_barrier(0);
        }
    }

    // ---- epilogue: NORMALIZED per-half bf16 y + per-row l ----
    float ltot = l_run + __shfl_xor(l_run, 32);
    if (h == 0) lP[((size_t)kt * 8 + b) * NN + q0 + lq] = ltot;
    float inv = 1.0f / ltot;

    ushort* yp = yP + (size_t)kt * ((size_t)BB * NN * CI);
    const size_t qb = ((size_t)b * NN + q0 + lq) * CI;
#pragma unroll
    for (int ct = 0; ct < 4; ct++)
#pragma unroll
        for (int r4 = 0; r4 < 4; r4++) {
            uint2 hw = make_uint2(
                pk2(ya[ct][r4 * 4 + 0] * inv, ya[ct][r4 * 4 + 1] * inv),
                pk2(ya[ct][r4 * 4 + 2] * inv, ya[ct][r4 * 4 + 3] * inv));
            int co = 32 * ct + 8 * r4 + 4 * h;
            *(uint2*)(yp + qb + co) = hw;
        }
}

// ---------------------------------------------------------------------------
// Kernel 3: merged out-projection with LDS pre-combine (proven). Stages both
// k-half results, combines in LDS with the proven ymerge formula,
// single-GEMM, BN + residual.
// ---------------------------------------------------------------------------
__global__ __launch_bounds__(256, 2) void outproj_mfma(
    const ushort* __restrict__ yP, const float* __restrict__ lP,
    const uint4* __restrict__ wo_h, const uint4* __restrict__ wo_l,
    const float* __restrict__ scale, const float* __restrict__ shift,
    const float* __restrict__ x, float* __restrict__ out)
{
    __shared__ __align__(16) char ysm[32768];
    const int t  = threadIdx.x;
    const int w  = t >> 6, l = t & 63;
    const int lq = l & 31, h = l >> 5;
    const int b  = blockIdx.x >> 6;
    const int n0 = (blockIdx.x & 63) << 6;
    const size_t arr = (size_t)BB * NN * CI;

    {
#pragma unroll
        for (int j = 0; j < 4; j++) {
            int idx = w * 64 + j * 256 + l;
            int row = idx >> 4, u = idx & 15;
            size_t srow = ((size_t)b * NN + n0 + row) * CI;
            int cb = 16 * (u ^ (row & 15));
            gload16((const char*)yP + srow * 2 + cb, ysm + (w * 64 + j * 256) * 16);
            gload16((const char*)(yP + arr) + srow * 2 + cb,
                    ysm + 16384 + (w * 64 + j * 256) * 16);
        }
    }
    __syncthreads();

    {
#pragma unroll
        for (int j = 0; j < 4; j++) {
            int idx = j * 256 + t;
            int row = idx >> 4;
            int n = n0 + row;
            float lA = lP[(size_t)b * NN + n];
            float lB = lP[(size_t)(8 + b) * NN + n];
            float s = 1.0f / (lA + lB);
            float aA = lA * s, aB = lB * s;
            uint4 va = *(const uint4*)(ysm + idx * 16);
            uint4 vb = *(const uint4*)(ysm + 16384 + idx * 16);
            const uint* pa = (const uint*)&va;
            const uint* pb = (const uint*)&vb;
            uint ho[4];
#pragma unroll
            for (int k = 0; k < 4; k++) {
                float v0 = aA * bflo(pa[k]) + aB * bflo(pb[k]);
                float v1 = aA * bfhi(pa[k]) + aB * bfhi(pb[k]);
                ho[k] = pk2(v0, v1);
            }
            *(uint4*)(ysm + idx * 16) = make_uint4(ho[0], ho[1], ho[2], ho[3]);
        }
    }
    __syncthreads();

#pragma unroll
    for (int oi = 0; oi < 2; oi++) {
        const int ot = w + oi * 4;
        const int ob = ot * 32 + lq;
        f32x16 c0 = (f32x16)0.0f, c1 = (f32x16)0.0f;
#pragma unroll 2
        for (int cs = 0; cs < 8; cs++) {
            int wi = (cs * 2 + h) * 256 + ob;
            bf16x8 wfh = asbf8(wo_h[wi]), wfl = asbf8(wo_l[wi]);
            int xoff = lq * 256 + 16 * ((cs * 2 + h) ^ (lq & 15));
            bf16x8 y0 = asbf8(*(const uint4*)(ysm + xoff));
            bf16x8 y1 = asbf8(*(const uint4*)(ysm + 8192 + xoff));
            c0 = __builtin_amdgcn_mfma_f32_32x32x16_bf16(wfh, y0, c0, 0, 0, 0);
            c0 = __builtin_amdgcn_mfma_f32_32x32x16_bf16(wfl, y0, c0, 0, 0, 0);
            c1 = __builtin_amdgcn_mfma_f32_32x32x16_bf16(wfh, y1, c1, 0, 0, 0);
            c1 = __builtin_amdgcn_mfma_f32_32x32x16_bf16(wfl, y1, c1, 0, 0, 0);
        }
#pragma unroll
        for (int ns = 0; ns < 2; ns++) {
            const f32x16& av = ns ? c1 : c0;
#pragma unroll
            for (int r = 0; r < 16; r++) {
                int o = ot * 32 + (r & 3) + 8 * (r >> 2) + 4 * h;
                size_t ai = ((size_t)b * CC + o) * NN + n0 + ns * 32 + lq;
                out[ai] = av[r] * scale[o] + shift[o] + x[ai];
            }
        }
    }
}

extern "C" void kernel_launch(void* const* d_in, const int* in_sizes, int n_in,
                              void* d_out, int out_size, void* d_ws, size_t ws_size,
                              hipStream_t stream) {
    const float* x       = (const float*)d_in[0];
    const float* w_g     = (const float*)d_in[1];
    const float* b_g     = (const float*)d_in[2];
    const float* w_theta = (const float*)d_in[3];
    const float* b_theta = (const float*)d_in[4];
    const float* w_phi   = (const float*)d_in[5];
    const float* b_phi   = (const float*)d_in[6];
    const float* w_out   = (const float*)d_in[7];
    const float* b_out   = (const float*)d_in[8];
    const float* bn_g    = (const float*)d_in[9];
    const float* bn_b    = (const float*)d_in[10];
    const float* bn_m    = (const float*)d_in[11];
    const float* bn_v    = (const float*)d_in[12];
    float* out = (float*)d_out;

    const size_t arr = (size_t)BB * NN * CI;
    ushort* thw   = (ushort*)d_ws;                  // fp16 theta,      8 MiB
    ushort* phiw  = thw + arr;                      // fp16 phi,        8 MiB
    ushort* gTw   = phiw + arr;                     // bf16 gT,         8 MiB
    ushort* yPb   = gTw + arr;                      // bf16 y halves,  16 MiB
    uint4*  wt_h  = (uint4*)(yPb + 2 * arr);
    uint4*  wt_l  = wt_h + 4096;
    uint4*  wp_h  = wt_l + 4096;
    uint4*  wp_l  = wp_h + 4096;
    uint4*  wg_h  = wp_l + 4096;
    uint4*  wg_l  = wg_h + 4096;
    uint4*  wo_h  = wg_l + 4096;
    uint4*  wo_l  = wo_h + 4096;
    float*  scl   = (float*)(wo_l + 4096);
    float*  shf   = scl + 256;
    float*  lPb   = shf + 256;                      // l halves, 256 KiB

    wconv_kernel<<<65, 256, 0, stream>>>(
        w_theta, w_phi, w_g, w_out, bn_g, bn_b, bn_m, bn_v, b_out,
        wt_h, wt_l, wp_h, wp_l, wg_h, wg_l, wo_h, wo_l, scl, shf);
    proj3_mfma<<<BB * 64, 256, 0, stream>>>(
        x, wt_h, wt_l, wp_h, wp_l, wg_h, wg_l, b_theta, b_phi, b_g,
        thw, phiw, gTw);
    attn_mfma<<<512, 256, 0, stream>>>(thw, phiw, gTw, yPb, lPb);
    outproj_mfma<<<BB * 64, 256, 0, stream>>>(
        yPb, lPb, wo_h, wo_l, scl, shf, x, out);
}